// Round 10
// baseline (242.026 us; speedup 1.0000x reference)
//
#include <hip/hip_runtime.h>
#include <math.h>

// LightweightConv: B=16, T=4000, C=512, H=8, K=31, PAD=15.
// out[b,t,c] = sum_k wn[c%8][k] * x[b, t-15+k, c] + bias[c%8],  wn = softmax(w)
// R7 evidence: latency-bound. VGPR=44 -> compiler sinks reg-window loads
// (~2-3 in flight); traffic -40% (XCD swizzle, FETCH 64MB) changed dur 0%.
// R8 fix: LDS-FIFO staging via global_load_lds (no VGPR dest -> cannot be
// sunk; 12x 1KB DMA all outstanding per wave), per-wave private slot (no
// __syncthreads), scatter-form compute (value consumed into 16 acc chains).

constexpr int NB   = 16;
constexpr int NT   = 4000;
constexpr int NC   = 512;
constexpr int NH   = 8;
constexpr int NK   = 31;
constexpr int CPAD = 15;

constexpr int CH    = 16;             // outputs per thread
constexpr int WIN   = CH + NK - 1;    // 46 rows read (t0-15 .. t0+30)
constexpr int ROWS4 = 48;             // rows staged (x4-padded; 46,47 never read)
constexpr int NTC   = NT / CH;        // 250
constexpr int NCG   = NC / 256;       // 2
constexpr int NWG   = NTC * NCG * NB; // 8000 (divisible by 8)
constexpr int NXCD  = 8;

// --- pre-kernel: softmax-normalize the (8,31) weight table into d_ws ---
__global__ __launch_bounds__(64) void softmax_w_kernel(
    const float* __restrict__ w, float* __restrict__ wn)
{
    const int h = threadIdx.x;
    if (h >= NH) return;
    float v[NK];
    float m = -1e30f;
    #pragma unroll
    for (int k = 0; k < NK; ++k) { v[k] = w[h * NK + k]; m = fmaxf(m, v[k]); }
    float s = 0.0f;
    #pragma unroll
    for (int k = 0; k < NK; ++k) { v[k] = __expf(v[k] - m); s += v[k]; }
    const float inv = 1.0f / s;
    #pragma unroll
    for (int k = 0; k < NK; ++k) wn[h * NK + k] = v[k] * inv;
}

// --- main kernel ---
// Block = 256 thr = 4 waves; wave stages/computes its own 64-channel slice.
// LDS slot per wave: ROWS4 x 64ch x 4B = 12288 B (layout: 4-row groups of
// 1024 B, matching dma16's base + lane*16 linear write). Block = 49152 B.
__global__ __launch_bounds__(256, 3) void lconv_kernel(
    const float* __restrict__ x,
    const float* __restrict__ wn,
    const float* __restrict__ bias,
    float* __restrict__ out)
{
    __shared__ float tile[4 * ROWS4 * 64];   // 49152 B

    // Bijective XCD swizzle (R7-verified: FETCH 183->64 MB): consecutive
    // t-chunks land on the same XCD -> halo re-reads hit its private L2.
    const int orig = blockIdx.x;
    const int lin  = (orig % NXCD) * (NWG / NXCD) + orig / NXCD;
    const int tc   = lin % NTC;
    const int rest = lin / NTC;
    const int cg   = rest % NCG;
    const int b    = rest / NCG;

    const int tid   = threadIdx.x;
    const int wv    = tid >> 6;
    const int ln    = tid & 63;
    const int c     = cg * 256 + tid;        // this thread's channel
    const int h     = c & (NH - 1);
    const int t0    = tc * CH;
    const int cbase = cg * 256 + wv * 64;    // wave's channel base

    float* wtile = &tile[wv * (ROWS4 * 64)];
    const float* xg = x + (size_t)b * NT * NC;

    if (tc >= 1 && tc <= NTC - 3) {
        // Interior (247/250 blocks): 12 x width-16 DMA, each stages 4 rows
        // x 64 ch = 1 KB. LDS dest linear (base + lane*16); global per-lane:
        // lanes 0-15 -> row 4i+0, 16-31 -> 4i+1, ... each lane 16 B of row.
        #pragma unroll
        for (int i = 0; i < ROWS4 / 4; ++i) {
            const int t = t0 - CPAD + 4 * i + (ln >> 4);
            const float* g = xg + (size_t)t * NC + cbase + (ln & 15) * 4;
            __builtin_amdgcn_global_load_lds(
                (const __attribute__((address_space(1))) void*)g,
                (__attribute__((address_space(3))) void*)&wtile[i * 256],
                16, 0, 0);
        }
    } else {
        // Edge (tc in {0,248,249}): per-row width-4 DMA for valid rows,
        // ds_write zeros for out-of-range rows. t is wave-uniform.
        #pragma unroll 1
        for (int r = 0; r < WIN; ++r) {
            const int t = t0 - CPAD + r;
            float* dst = &wtile[(r >> 2) * 256 + (r & 3) * 64];
            if (t >= 0 && t < NT) {
                const float* g = xg + (size_t)t * NC + cbase + ln;
                __builtin_amdgcn_global_load_lds(
                    (const __attribute__((address_space(1))) void*)g,
                    (__attribute__((address_space(3))) void*)dst,
                    4, 0, 0);
            } else {
                dst[ln] = 0.0f;
            }
        }
    }

    // Weights/bias global loads overlap the in-flight DMA.
    float wr[NK];
    #pragma unroll
    for (int k = 0; k < NK; ++k) wr[k] = wn[h * NK + k];
    const float bv = bias[h];

    // Drain DMA (and weight loads): vmcnt(0), lgkm/exp don't-care.
    __builtin_amdgcn_s_waitcnt(0x0F70);
    __builtin_amdgcn_sched_barrier(0);

    // Scatter-form conv: each LDS value feeds up to 16 independent acc
    // chains -> no register window, nothing for the scheduler to sink.
    float acc[CH];
    #pragma unroll
    for (int j = 0; j < CH; ++j) acc[j] = bv;

    #pragma unroll
    for (int r = 0; r < WIN; ++r) {
        const float v = wtile[(r >> 2) * 256 + (r & 3) * 64 + ln];
        #pragma unroll
        for (int j = 0; j < CH; ++j) {
            const int k = r - j;             // tap index for output j
            if (k >= 0 && k < NK)
                acc[j] = fmaf(v, wr[k], acc[j]);
        }
    }

    float* ob = out + (size_t)b * NT * NC + c;
    #pragma unroll
    for (int j = 0; j < CH; ++j)
        ob[(size_t)(t0 + j) * NC] = acc[j];
}

extern "C" void kernel_launch(void* const* d_in, const int* in_sizes, int n_in,
                              void* d_out, int out_size, void* d_ws, size_t ws_size,
                              hipStream_t stream) {
    const float* x    = (const float*)d_in[0];   // (B, T, C) f32
    const float* w    = (const float*)d_in[1];   // (H, 1, K) f32
    const float* bias = (const float*)d_in[2];   // (H,) f32
    float*       out  = (float*)d_out;           // (B, T, C) f32
    float*       wnrm = (float*)d_ws;            // 8*31 f32 normalized weights

    softmax_w_kernel<<<1, 64, 0, stream>>>(w, wnrm);
    lconv_kernel<<<NWG, 256, 0, stream>>>(x, wnrm, bias, out);
}